// Round 7
// baseline (109.378 us; speedup 1.0000x reference)
//
#include <hip/hip_runtime.h>
#include <math.h>

#define BB 32
#define CC 1024
#define NN 4096
#define NSC 16          // sort sub-chunks per row (verified round-4 shape)
#define SCK 256         // points per sub-chunk
#define NBR 8           // blocks per row
#define POISON32 0xAAAAAAAAu   // harness re-poisons d_ws to 0xAA bytes

typedef unsigned long long u64;

// Monotone float encoding: key order == (value asc, smaller index wins ties via
// larger (4095-idx)). All finite floats map to mono > 0.
__device__ __forceinline__ u64 enc_key(float v, int gidx) {
    unsigned u = __float_as_uint(v);
    unsigned mono = (u & 0x80000000u) ? ~u : (u | 0x80000000u);
    return ((u64)mono << 12) | (unsigned)(4095 - gidx);
}

// ---------------------------------------------------------------------------
// Fused single kernel. grid = 32*8 = 256 blocks x 1024 threads (1 block/CU,
// 4 waves/SIMD -- the occupancy phase A needs per round-5/6 evidence).
// Phase A: block (b,k): waves 0-7 -> sub-chunk 2k, waves 8-15 -> 2k+1; each
//   thread does 2 channels x 256 points with the bit-verified group-of-4
//   argmax; writes pkeys via contention-free device-scope atomicExch.
// Election: 8 blocks/row; atomicAdd on 0xAA-poisoned rowdone[b]; the unique
//   last arriver (old == POISON+7) runs phase B (no spin -> no deadlock).
// Phase B: round-4 k2 body verbatim (1024 threads, int H, 16 chunks).
// ---------------------------------------------------------------------------
__global__ __launch_bounds__(1024) void k_fused(
    const float* __restrict__ x, const float* __restrict__ W,
    float* __restrict__ out_x, float* __restrict__ counts,
    float* __restrict__ imp2, float* __restrict__ ent,
    u64* __restrict__ pkeys, unsigned* __restrict__ rowdone) {

    __shared__ int   cnt[NN];               // 16 KB
    __shared__ int   H[NSC * (CC + 1)];     // 65.6 KB
    __shared__ int   exvs[CC + 1];          // 4.1 KB
    __shared__ int   wsum[16];
    __shared__ float esum[16];
    __shared__ int   lastflag;

    const int bid = blockIdx.x;
    const int b = bid >> 3, k = bid & 7;
    const int tid = threadIdx.x;
    const int wv = tid >> 6, lane = tid & 63;

    // copy this block's x slice (512 points x 3 dims = 384 float4) to out_x
    if (tid < 384) {
        int d = tid >> 7;                 // 0..2
        int off = (tid & 127) << 2;       // 0..508
        const size_t p = (size_t)(b * 3 + d) * NN + k * 512 + off;
        *(float4*)(out_x + p) = *(const float4*)(x + p);
    }

    // ======================= phase A: partial argmax =======================
    const int ph = tid >> 9;              // wave-uniform (waves 0-7 / 8-15)
    const int s  = k * 2 + ph;            // sub-chunk in [0,16)
    const int cA = tid & 511;
    const int cB = cA + 512;
    const float* xb = x + (size_t)b * 3 * NN + s * SCK;

    const float w0a = W[cA * 3 + 0], w1a = W[cA * 3 + 1], w2a = W[cA * 3 + 2];
    const float w0b = W[cB * 3 + 0], w1b = W[cB * 3 + 1], w2b = W[cB * 3 + 2];

    float bA = -INFINITY, bB = -INFINITY;
    int gA = 0, gB = 0;

    #pragma unroll 4
    for (int n = 0; n < SCK; n += 4) {
        // wave-uniform addresses -> scalar-cache loads, shared by 8 waves
        float4 a0 = *(const float4*)(xb + n);
        float4 a1 = *(const float4*)(xb + NN + n);
        float4 a2 = *(const float4*)(xb + 2 * NN + n);
        {   // channel cA -- identical fp contraction to rounds 1-6
            float v0 = fmaf(w2a, a2.x, fmaf(w1a, a1.x, w0a * a0.x));
            float v1 = fmaf(w2a, a2.y, fmaf(w1a, a1.y, w0a * a0.y));
            float v2 = fmaf(w2a, a2.z, fmaf(w1a, a1.z, w0a * a0.z));
            float v3 = fmaf(w2a, a2.w, fmaf(w1a, a1.w, w0a * a0.w));
            float gm = fmaxf(fmaxf(v0, v1), fmaxf(v2, v3));   // exact
            if (gm > bA) { bA = gm; gA = n; }                 // first group wins
        }
        {   // channel cB
            float v0 = fmaf(w2b, a2.x, fmaf(w1b, a1.x, w0b * a0.x));
            float v1 = fmaf(w2b, a2.y, fmaf(w1b, a1.y, w0b * a0.y));
            float v2 = fmaf(w2b, a2.z, fmaf(w1b, a1.z, w0b * a0.z));
            float v3 = fmaf(w2b, a2.w, fmaf(w1b, a1.w, w0b * a0.w));
            float gm = fmaxf(fmaxf(v0, v1), fmaxf(v2, v3));
            if (gm > bB) { bB = gm; gB = n; }
        }
    }
    {   // tail: resolve in-group position, bit-exact recompute (channel cA)
        float4 a0 = *(const float4*)(xb + gA);
        float4 a1 = *(const float4*)(xb + NN + gA);
        float4 a2 = *(const float4*)(xb + 2 * NN + gA);
        float v0 = fmaf(w2a, a2.x, fmaf(w1a, a1.x, w0a * a0.x));
        float v1 = fmaf(w2a, a2.y, fmaf(w1a, a1.y, w0a * a0.y));
        float v2 = fmaf(w2a, a2.z, fmaf(w1a, a1.z, w0a * a0.z));
        int j = (v0 == bA) ? 0 : (v1 == bA) ? 1 : (v2 == bA) ? 2 : 3;
        atomicExch(&pkeys[(size_t)(b * NSC + s) * CC + cA],
                   enc_key(bA, s * SCK + gA + j));   // contention-free, coherent
    }
    {   // tail (channel cB)
        float4 a0 = *(const float4*)(xb + gB);
        float4 a1 = *(const float4*)(xb + NN + gB);
        float4 a2 = *(const float4*)(xb + 2 * NN + gB);
        float v0 = fmaf(w2b, a2.x, fmaf(w1b, a1.x, w0b * a0.x));
        float v1 = fmaf(w2b, a2.y, fmaf(w1b, a1.y, w0b * a0.y));
        float v2 = fmaf(w2b, a2.z, fmaf(w1b, a1.z, w0b * a0.z));
        int j = (v0 == bB) ? 0 : (v1 == bB) ? 1 : (v2 == bB) ? 2 : 3;
        atomicExch(&pkeys[(size_t)(b * NSC + s) * CC + cB],
                   enc_key(bB, s * SCK + gB + j));
    }

    // ============ last-arriver election (no spin -> no deadlock) ===========
    __syncthreads();   // s_waitcnt vmcnt(0): all 16 waves' atomicExch complete
    if (tid == 0) {
        __threadfence();
        unsigned old = atomicAdd(&rowdone[b], 1u);
        lastflag = (old == POISON32 + (NBR - 1)) ? 1 : 0;   // unique per row
    }
    __syncthreads();
    if (!lastflag) return;

    // ================= phase B: round-4 k2 body (verified) =================
    __threadfence();   // acquire side
    #pragma unroll
    for (int i = 0; i < 4; ++i) cnt[tid + i * 1024] = 0;
    for (int i = tid; i < NSC * (CC + 1); i += 1024) H[i] = 0;
    __syncthreads();

    // combine 16 partial keys for channel c = tid -> winner -> LDS hist
    {
        u64 bestk = 0;
        u64* pk = pkeys + (size_t)b * NSC * CC + tid;
        #pragma unroll
        for (int s2 = 0; s2 < NSC; ++s2) {
            u64 key = __hip_atomic_load(&pk[s2 * CC], __ATOMIC_RELAXED,
                                        __HIP_MEMORY_SCOPE_AGENT);
            bestk = (key > bestk) ? key : bestk;
        }
        int idx = 4095 - (int)(bestk & 0xFFFu);
        atomicAdd(&cnt[idx], 1);
    }
    __syncthreads();

    // counts output (coalesced float4) + per-chunk hists (wave wv <-> chunk wv)
    {
        float4 cf;
        cf.x = (float)cnt[4 * tid + 0];
        cf.y = (float)cnt[4 * tid + 1];
        cf.z = (float)cnt[4 * tid + 2];
        cf.w = (float)cnt[4 * tid + 3];
        *(float4*)(counts + (size_t)b * NN + 4 * tid) = cf;

        int h0 = 0, h1 = 0;
        #pragma unroll
        for (int r = 0; r < 4; ++r) {
            int ci = cnt[wv * SCK + r * 64 + lane];
            u64 m0 = __ballot(ci == 0);
            u64 m1 = __ballot(ci == 1);
            if (lane == 0) { h0 += (int)__popcll(m0); h1 += (int)__popcll(m1); }
            if (ci > 1) atomicAdd(&H[wv * (CC + 1) + ci], 1);
        }
        if (lane == 0) {           // bins 0/1 never touched by the atomics
            H[wv * (CC + 1) + 0] = h0;
            H[wv * (CC + 1) + 1] = h1;
        }
    }
    __syncthreads();

    // transform H[w][v] -> prefix over chunks (value v = tid); wave scans
    int g_v, run1024 = 0;
    {
        int run = 0;
        #pragma unroll
        for (int w = 0; w < NSC; ++w) {
            int t = H[w * (CC + 1) + tid];
            H[w * (CC + 1) + tid] = run;
            run += t;
        }
        g_v = run;
        if (tid == 0) {
            int run2 = 0;
            #pragma unroll
            for (int w = 0; w < NSC; ++w) {
                int t = H[w * (CC + 1) + CC];
                H[w * (CC + 1) + CC] = run2;
                run2 += t;
            }
            run1024 = run2;
        }
    }
    const float S = 1024.0f + 4096.0f * 1e-6f;   // sum(counts + eps) exactly
    float e = 0.f;
    if (g_v) {
        float p = ((float)tid + 1e-6f) / S;
        e = (float)g_v * p * log2f(p);
    }
    if (tid == 0 && run1024) {
        float p = (1024.0f + 1e-6f) / S;
        e += (float)run1024 * p * log2f(p);
    }
    int incl = g_v;                              // wave inclusive scan
    #pragma unroll
    for (int d = 1; d < 64; d <<= 1) {
        int t = __shfl_up(incl, d, 64);
        if (lane >= d) incl += t;
    }
    float er = e;                                // wave entropy reduce
    #pragma unroll
    for (int d = 32; d > 0; d >>= 1)
        er += __shfl_down(er, d, 64);
    if (lane == 63) wsum[wv] = incl;
    if (lane == 0)  esum[wv] = er;
    __syncthreads();

    // wave0: exclusive scan of 16 wave sums; wave1: entropy total -> ent[b]
    if (wv == 0) {
        int v = (lane < 16) ? wsum[lane] : 0;
        int inc2 = v;
        #pragma unroll
        for (int d = 1; d < 16; d <<= 1) {
            int t = __shfl_up(inc2, d, 64);
            if (lane >= d) inc2 += t;
        }
        if (lane < 16) wsum[lane] = inc2 - v;    // exclusive wave prefix
    } else if (wv == 1) {
        float v = (lane < 16) ? esum[lane] : 0.f;
        #pragma unroll
        for (int d = 8; d > 0; d >>= 1)
            v += __shfl_down(v, d, 64);
        if (lane == 0) ent[b] = -v / 12.0f;      // log2(4096) = 12
    }
    __syncthreads();

    // exclusive value prefix -> LDS
    exvs[tid] = incl - g_v + wsum[wv];
    if (tid == 0) exvs[CC] = NN - run1024;
    __syncthreads();

    // stable placement: wave wv <-> chunk wv, 4 batches of 64 in index order;
    // rank among equals via match-any ballot; cursor per (chunk,value) in H.
    {
        const u64 lt = (1ull << lane) - 1ull;
        float* orow = imp2 + (size_t)b * NN;
        int* Hrow = &H[wv * (CC + 1)];
        for (int r = 0; r < 4; ++r) {
            const int n = wv * SCK + r * 64 + lane;
            const int ci = cnt[n];
            u64 eq = 0, todo = ~0ull;
            for (;;) {                        // ~#distinct values iterations
                int src = (int)__builtin_ctzll(todo);
                int v0 = __shfl(ci, src, 64);
                u64 m = __ballot(ci == v0);
                if (ci == v0) eq = m;
                todo &= ~m;
                if (!todo) break;
            }
            int rank = (int)__popcll(eq & lt);
            int base = Hrow[ci];              // broadcast among equals
            orow[exvs[ci] + base + rank] = (float)n;
            if ((eq >> lane) == 1ull)         // highest equal lane updates
                Hrow[ci] = base + (int)__popcll(eq);
        }
    }
}

extern "C" void kernel_launch(void* const* d_in, const int* in_sizes, int n_in,
                              void* d_out, int out_size, void* d_ws, size_t ws_size,
                              hipStream_t stream) {
    const float* x = (const float*)d_in[0];    // [32,3,4096]
    const float* W = (const float*)d_in[1];    // [1024,3]
    float* out    = (float*)d_out;
    float* out_x  = out;                        // 393216
    float* counts = out + (size_t)BB * 3 * NN;  // 131072
    float* imp2   = counts + (size_t)BB * NN;   // 131072
    float* ent    = imp2 + (size_t)BB * NN;     // 32

    u64* pkeys = (u64*)d_ws;                    // 32*16*1024 u64 = 4 MB
    unsigned* rowdone = (unsigned*)(pkeys + (size_t)BB * NSC * CC);  // 32 u32

    k_fused<<<BB * NBR, 1024, 0, stream>>>(x, W, out_x, counts, imp2, ent,
                                           pkeys, rowdone);
}

// Round 8
// 89.944 us; speedup vs baseline: 1.2161x; 1.2161x over previous
//
#include <hip/hip_runtime.h>
#include <math.h>

#define BB 32
#define CC 1024
#define NN 4096
#define NCH 16          // n-chunks per row
#define CHK 256         // points per chunk

typedef unsigned long long u64;

// Monotone float encoding: key order == (value asc, smaller index wins ties via
// larger (4095-idx)). All finite floats map to mono > 0.
__device__ __forceinline__ u64 enc_key(float v, int gidx) {
    unsigned u = __float_as_uint(v);
    unsigned mono = (u & 0x80000000u) ? ~u : (u | 0x80000000u);
    return ((u64)mono << 12) | (unsigned)(4095 - gidx);
}

// ---------------------------------------------------------------------------
// K1: partial argmax. grid = 32 rows * 16 chunks * 2 channel-halves = 1024
// blocks x 256 threads -> 4 blocks/CU (round-4 had 2; rounds 5-7 showed the
// loop is latency-bound there). Chunk index stays BLOCK-uniform -> x loads go
// through the scalar cache (the property round-7's fusion lost). Each thread:
// 2 channels x 256 points, bit-identical group-of-4 argmax. pkeys layout
// unchanged from round 4 (NCH=16) so k2 stays the verified shape.
// ---------------------------------------------------------------------------
__global__ __launch_bounds__(256) void k1_argmax_partial(
    const float* __restrict__ x, const float* __restrict__ W,
    float* __restrict__ out_x, u64* __restrict__ pkeys) {
    const int bid  = blockIdx.x;
    const int b    = bid >> 5;
    const int k    = (bid >> 1) & 15;     // chunk: block-uniform
    const int half = bid & 1;             // channel half
    const int tid  = threadIdx.x;

    // copy chunk through to out_x once per (b,k): half==0 blocks only
    if (half == 0 && tid < 192) {
        int d = tid >> 6;
        int off = (tid & 63) << 2;
        const size_t p = (size_t)(b * 3 + d) * NN + k * CHK + off;
        *(float4*)(out_x + p) = *(const float4*)(x + p);
    }

    const int cA = half * 512 + tid;          // 2 channels per thread
    const int cB = cA + 256;
    const float w0a = W[cA * 3 + 0], w1a = W[cA * 3 + 1], w2a = W[cA * 3 + 2];
    const float w0b = W[cB * 3 + 0], w1b = W[cB * 3 + 1], w2b = W[cB * 3 + 2];

    const float* xb = x + (size_t)b * 3 * NN + k * CHK;
    float bA = -INFINITY, bB = -INFINITY;
    int gA = 0, gB = 0;

    #pragma unroll 4
    for (int n = 0; n < CHK; n += 4) {
        // block-uniform addresses -> s_load through scalar cache
        float4 a0 = *(const float4*)(xb + n);
        float4 a1 = *(const float4*)(xb + NN + n);
        float4 a2 = *(const float4*)(xb + 2 * NN + n);
        {   // identical fp contraction to rounds 1-7 (bit-matched reference)
            float v0 = fmaf(w2a, a2.x, fmaf(w1a, a1.x, w0a * a0.x));
            float v1 = fmaf(w2a, a2.y, fmaf(w1a, a1.y, w0a * a0.y));
            float v2 = fmaf(w2a, a2.z, fmaf(w1a, a1.z, w0a * a0.z));
            float v3 = fmaf(w2a, a2.w, fmaf(w1a, a1.w, w0a * a0.w));
            float gm = fmaxf(fmaxf(v0, v1), fmaxf(v2, v3));   // exact
            if (gm > bA) { bA = gm; gA = n; }                 // first group wins
        }
        {
            float v0 = fmaf(w2b, a2.x, fmaf(w1b, a1.x, w0b * a0.x));
            float v1 = fmaf(w2b, a2.y, fmaf(w1b, a1.y, w0b * a0.y));
            float v2 = fmaf(w2b, a2.z, fmaf(w1b, a1.z, w0b * a0.z));
            float v3 = fmaf(w2b, a2.w, fmaf(w1b, a1.w, w0b * a0.w));
            float gm = fmaxf(fmaxf(v0, v1), fmaxf(v2, v3));
            if (gm > bB) { bB = gm; gB = n; }
        }
    }

    // resolve position within winning group (bit-exact recompute) + store
    {
        float4 a0 = *(const float4*)(xb + gA);
        float4 a1 = *(const float4*)(xb + NN + gA);
        float4 a2 = *(const float4*)(xb + 2 * NN + gA);
        float v0 = fmaf(w2a, a2.x, fmaf(w1a, a1.x, w0a * a0.x));
        float v1 = fmaf(w2a, a2.y, fmaf(w1a, a1.y, w0a * a0.y));
        float v2 = fmaf(w2a, a2.z, fmaf(w1a, a1.z, w0a * a0.z));
        int j = (v0 == bA) ? 0 : (v1 == bA) ? 1 : (v2 == bA) ? 2 : 3;
        pkeys[(size_t)(b * NCH + k) * CC + cA] = enc_key(bA, k * CHK + gA + j);
    }
    {
        float4 a0 = *(const float4*)(xb + gB);
        float4 a1 = *(const float4*)(xb + NN + gB);
        float4 a2 = *(const float4*)(xb + 2 * NN + gB);
        float v0 = fmaf(w2b, a2.x, fmaf(w1b, a1.x, w0b * a0.x));
        float v1 = fmaf(w2b, a2.y, fmaf(w1b, a1.y, w0b * a0.y));
        float v2 = fmaf(w2b, a2.z, fmaf(w1b, a1.z, w0b * a0.z));
        int j = (v0 == bB) ? 0 : (v1 == bB) ? 1 : (v2 == bB) ? 2 : 3;
        pkeys[(size_t)(b * NCH + k) * CC + cB] = enc_key(bB, k * CHK + gB + j);
    }
}

// ---------------------------------------------------------------------------
// K2: per-row mega-kernel incl. placement (round-4 verified body, untouched).
// grid = 32 blocks x 1024 threads.
// ---------------------------------------------------------------------------
__global__ __launch_bounds__(1024) void k2_row_all(
    const u64* __restrict__ pkeys, float* __restrict__ counts,
    float* __restrict__ imp2, float* __restrict__ ent) {
    __shared__ int   cnt[NN];               // 16 KB: counts per point
    __shared__ int   H[NCH * (CC + 1)];     // 65.6 KB: hist -> chunk-prefix/cursor
    __shared__ int   exvs[CC + 1];          // 4.1 KB: exclusive value prefix
    __shared__ int   wsum[16];
    __shared__ float esum[16];

    const int b = blockIdx.x;
    const int tid = threadIdx.x;
    const int wv = tid >> 6, lane = tid & 63;

    // 1. zero
    #pragma unroll
    for (int i = 0; i < 4; ++i) cnt[tid + i * 1024] = 0;
    #pragma unroll
    for (int i = 0; i < 16; ++i) H[tid + i * 1024] = 0;   // 16384 of 16400
    if (tid < NCH * (CC + 1) - 16 * 1024) H[16 * 1024 + tid] = 0;
    __syncthreads();

    // 2. combine 16 partial keys for channel c = tid -> winner -> LDS hist
    {
        u64 bestk = 0;
        const u64* pk = pkeys + (size_t)b * NCH * CC + tid;
        #pragma unroll
        for (int k = 0; k < NCH; ++k) {
            u64 key = pk[k * CC];
            bestk = (key > bestk) ? key : bestk;
        }
        int idx = 4095 - (int)(bestk & 0xFFFu);
        atomicAdd(&cnt[idx], 1);
    }
    __syncthreads();

    // 3. write counts (coalesced float4) + per-chunk hist (wave w <-> chunk w)
    {
        float4 cf;
        cf.x = (float)cnt[4 * tid + 0];
        cf.y = (float)cnt[4 * tid + 1];
        cf.z = (float)cnt[4 * tid + 2];
        cf.w = (float)cnt[4 * tid + 3];
        *(float4*)(counts + (size_t)b * NN + 4 * tid) = cf;

        int h0 = 0, h1 = 0;
        #pragma unroll
        for (int r = 0; r < 4; ++r) {
            int ci = cnt[wv * CHK + r * 64 + lane];
            u64 m0 = __ballot(ci == 0);
            u64 m1 = __ballot(ci == 1);
            if (lane == 0) { h0 += (int)__popcll(m0); h1 += (int)__popcll(m1); }
            if (ci > 1) atomicAdd(&H[wv * (CC + 1) + ci], 1);
        }
        if (lane == 0) {           // bins 0/1 never touched by the atomics
            H[wv * (CC + 1) + 0] = h0;
            H[wv * (CC + 1) + 1] = h1;
        }
    }
    __syncthreads();

    // 4. transform H[w][v] -> prefix over chunks (per value v=tid); row total
    //    g_v; entropy partial; wave-level shuffle scan + reduce (no barriers)
    int g_v, run1024 = 0;
    {
        int run = 0;
        #pragma unroll
        for (int w = 0; w < NCH; ++w) {
            int t = H[w * (CC + 1) + tid];
            H[w * (CC + 1) + tid] = run;     // prefix of chunks < w
            run += t;
        }
        g_v = run;
        if (tid == 0) {                      // value bin 1024 handled by thread 0
            int run2 = 0;
            #pragma unroll
            for (int w = 0; w < NCH; ++w) {
                int t = H[w * (CC + 1) + CC];
                H[w * (CC + 1) + CC] = run2;
                run2 += t;
            }
            run1024 = run2;
        }
    }
    const float S = 1024.0f + 4096.0f * 1e-6f;   // sum(counts)+N*eps exactly
    float e = 0.f;
    if (g_v) {
        float p = ((float)tid + 1e-6f) / S;
        e = (float)g_v * p * log2f(p);
    }
    if (tid == 0 && run1024) {
        float p = (1024.0f + 1e-6f) / S;
        e += (float)run1024 * p * log2f(p);
    }
    int incl = g_v;                              // wave inclusive scan
    #pragma unroll
    for (int d = 1; d < 64; d <<= 1) {
        int t = __shfl_up(incl, d, 64);
        if (lane >= d) incl += t;
    }
    float er = e;                                // wave entropy reduce
    #pragma unroll
    for (int d = 32; d > 0; d >>= 1)
        er += __shfl_down(er, d, 64);
    if (lane == 63) wsum[wv] = incl;
    if (lane == 0)  esum[wv] = er;
    __syncthreads();

    // 5. wave0: exclusive scan of 16 wave sums; wave1: entropy total -> ent[b]
    if (wv == 0) {
        int v = (lane < 16) ? wsum[lane] : 0;
        int inc2 = v;
        #pragma unroll
        for (int d = 1; d < 16; d <<= 1) {
            int t = __shfl_up(inc2, d, 64);
            if (lane >= d) inc2 += t;
        }
        if (lane < 16) wsum[lane] = inc2 - v;    // exclusive wave prefix
    } else if (wv == 1) {
        float v = (lane < 16) ? esum[lane] : 0.f;
        #pragma unroll
        for (int d = 8; d > 0; d >>= 1)
            v += __shfl_down(v, d, 64);
        if (lane == 0) ent[b] = -v / 12.0f;      // log2(4096) = 12
    }
    __syncthreads();

    // 6. exclusive value prefix -> LDS
    exvs[tid] = incl - g_v + wsum[wv];
    if (tid == 0) exvs[CC] = NN - run1024;
    __syncthreads();

    // 7. stable placement: wave w <-> chunk w; 4 batches of 64 points in index
    //    order. Rank among equals within batch via match-any ballot; rank
    //    across batches via per-(chunk,value) cursor in H (wave-private row).
    {
        const u64 ltmask = (1ull << lane) - 1ull;
        int* curw = &H[wv * (CC + 1)];
        float* orow = imp2 + (size_t)b * NN;
        for (int r = 0; r < 4; ++r) {
            const int n = wv * CHK + r * 64 + lane;
            const int ci = cnt[n];
            // match-any: eq = mask of lanes whose ci equals mine
            u64 eq = 0, todo = ~0ull;
            while (true) {                        // ~#distinct values iterations
                int src = (int)__builtin_ctzll(todo);
                int v0 = __shfl(ci, src, 64);
                u64 m = __ballot(ci == v0);
                if (ci == v0) eq = m;
                todo &= ~m;
                if (todo == 0ull) break;
            }
            int rank = (int)__popcll(eq & ltmask);
            int c0 = curw[ci];                    // broadcast-ish LDS read
            orow[c0 + exvs[ci] + rank] = (float)n;
            if ((eq >> lane) == 1ull)             // highest equal lane updates
                curw[ci] = c0 + (int)__popcll(eq);
        }
    }
}

extern "C" void kernel_launch(void* const* d_in, const int* in_sizes, int n_in,
                              void* d_out, int out_size, void* d_ws, size_t ws_size,
                              hipStream_t stream) {
    const float* x = (const float*)d_in[0];    // [32,3,4096]
    const float* W = (const float*)d_in[1];    // [1024,3]
    float* out    = (float*)d_out;
    float* out_x  = out;                        // 393216
    float* counts = out + (size_t)BB * 3 * NN;  // 131072
    float* imp2   = counts + (size_t)BB * NN;   // 131072
    float* ent    = imp2 + (size_t)BB * NN;     // 32

    u64* pkeys = (u64*)d_ws;                    // 32*16*1024 u64 = 4 MB

    k1_argmax_partial<<<BB * NCH * 2, 256, 0, stream>>>(x, W, out_x, pkeys);
    k2_row_all<<<BB, 1024, 0, stream>>>(pkeys, counts, imp2, ent);
}

// Round 9
// 82.066 us; speedup vs baseline: 1.3328x; 1.0960x over previous
//
#include <hip/hip_runtime.h>
#include <math.h>

#define BB 32
#define CC 1024
#define NN 4096
#define NCH 16          // n-chunks per row
#define CHK 256         // points per chunk

typedef unsigned long long u64;

// Monotone float encoding: key order == (value asc, smaller index wins ties via
// larger (4095-idx)). All finite floats map to mono > 0.
__device__ __forceinline__ u64 enc_key(float v, int gidx) {
    unsigned u = __float_as_uint(v);
    unsigned mono = (u & 0x80000000u) ? ~u : (u | 0x80000000u);
    return ((u64)mono << 12) | (unsigned)(4095 - gidx);
}

// Force a wave-uniform pointer into SGPRs so loads through it scalarize
// (s_load). Needed because the half-dependent base is thread-divergent in the
// compiler's view even though it is uniform within each wave.
__device__ __forceinline__ const float* uniform_ptr(const float* p) {
    unsigned lo = (unsigned)(uintptr_t)p;
    unsigned hi = (unsigned)((uintptr_t)p >> 32);
    lo = __builtin_amdgcn_readfirstlane(lo);
    hi = __builtin_amdgcn_readfirstlane(hi);
    return (const float*)(((uintptr_t)hi << 32) | (uintptr_t)lo);
}

// ---------------------------------------------------------------------------
// K1: partial argmax. grid = 32*16 = 512 blocks x 512 threads.
// Block (b,k): waves 0-3 scan points [0,128) of the chunk, waves 4-7 scan
// [128,256); 4 channels/thread. Loads per chunk = 8 waves x 96 = 768 — equal
// to round 4 (the r8 regression showed load count is what matters) — but at
// 4 waves/SIMD instead of 2, with the x base forced into SGPRs (s_load).
// Halves combine via LDS key table + max (key encodes first-index tie-break).
// ---------------------------------------------------------------------------
__global__ __launch_bounds__(512) void k1_argmax_partial(
    const float* __restrict__ x, const float* __restrict__ W,
    float* __restrict__ out_x, u64* __restrict__ pkeys) {
    __shared__ u64 kkey[CC];              // 8 KB
    const int bid = blockIdx.x;
    const int b = bid >> 4, k = bid & 15;
    const int tid = threadIdx.x;          // 0..511

    // copy chunk through to out_x (3 dims x 256 floats = 192 float4)
    if (tid < 192) {
        int d = tid >> 6;
        int off = (tid & 63) << 2;
        const size_t p = (size_t)(b * 3 + d) * NN + k * CHK + off;
        *(float4*)(out_x + p) = *(const float4*)(x + p);
    }

    const int h = tid >> 8;               // 0: waves 0-3, 1: waves 4-7
    const int t = tid & 255;

    float w0[4], w1[4], w2[4];
    #pragma unroll
    for (int q = 0; q < 4; ++q) {
        int c = q * 256 + t;
        w0[q] = W[c * 3 + 0];
        w1[q] = W[c * 3 + 1];
        w2[q] = W[c * 3 + 2];
    }

    // wave-uniform base -> SGPR via readfirstlane -> s_load path
    const float* xb = uniform_ptr(x + (size_t)b * 3 * NN + k * CHK + h * 128);

    float best[4] = {-INFINITY, -INFINITY, -INFINITY, -INFINITY};
    int gn[4] = {0, 0, 0, 0};

    #pragma unroll 4
    for (int n = 0; n < 128; n += 4) {
        float4 a0 = *(const float4*)(xb + n);
        float4 a1 = *(const float4*)(xb + NN + n);
        float4 a2 = *(const float4*)(xb + 2 * NN + n);
        #pragma unroll
        for (int q = 0; q < 4; ++q) {
            // identical fp contraction to rounds 1-8 (bit-matched reference)
            float v0 = fmaf(w2[q], a2.x, fmaf(w1[q], a1.x, w0[q] * a0.x));
            float v1 = fmaf(w2[q], a2.y, fmaf(w1[q], a1.y, w0[q] * a0.y));
            float v2 = fmaf(w2[q], a2.z, fmaf(w1[q], a1.z, w0[q] * a0.z));
            float v3 = fmaf(w2[q], a2.w, fmaf(w1[q], a1.w, w0[q] * a0.w));
            float gm = fmaxf(fmaxf(v0, v1), fmaxf(v2, v3));   // exact
            if (gm > best[q]) { best[q] = gm; gn[q] = n; }    // first group wins
        }
    }

    // resolve position within winning group (bit-exact recompute) -> key
    u64 mykey[4];
    #pragma unroll
    for (int q = 0; q < 4; ++q) {
        int n = gn[q];
        float4 a0 = *(const float4*)(xb + n);
        float4 a1 = *(const float4*)(xb + NN + n);
        float4 a2 = *(const float4*)(xb + 2 * NN + n);
        float v0 = fmaf(w2[q], a2.x, fmaf(w1[q], a1.x, w0[q] * a0.x));
        float v1 = fmaf(w2[q], a2.y, fmaf(w1[q], a1.y, w0[q] * a0.y));
        float v2 = fmaf(w2[q], a2.z, fmaf(w1[q], a1.z, w0[q] * a0.z));
        int j = (v0 == best[q]) ? 0 : (v1 == best[q]) ? 1 : (v2 == best[q]) ? 2 : 3;
        mykey[q] = enc_key(best[q], k * CHK + h * 128 + n + j);
    }

    // combine halves: key max == (value asc, first index on ties)
    if (h == 0) {
        #pragma unroll
        for (int q = 0; q < 4; ++q) kkey[q * 256 + t] = mykey[q];
    }
    __syncthreads();
    if (h == 1) {
        #pragma unroll
        for (int q = 0; q < 4; ++q) {
            u64 o = kkey[q * 256 + t];
            u64 f = (o > mykey[q]) ? o : mykey[q];
            pkeys[(size_t)(b * NCH + k) * CC + q * 256 + t] = f;  // coalesced
        }
    }
}

// ---------------------------------------------------------------------------
// K2: per-row mega-kernel incl. placement (round-4 verified body, untouched).
// grid = 32 blocks x 1024 threads.
// ---------------------------------------------------------------------------
__global__ __launch_bounds__(1024) void k2_row_all(
    const u64* __restrict__ pkeys, float* __restrict__ counts,
    float* __restrict__ imp2, float* __restrict__ ent) {
    __shared__ int   cnt[NN];               // 16 KB: counts per point
    __shared__ int   H[NCH * (CC + 1)];     // 65.6 KB: hist -> chunk-prefix/cursor
    __shared__ int   exvs[CC + 1];          // 4.1 KB: exclusive value prefix
    __shared__ int   wsum[16];
    __shared__ float esum[16];

    const int b = blockIdx.x;
    const int tid = threadIdx.x;
    const int wv = tid >> 6, lane = tid & 63;

    // 1. zero
    #pragma unroll
    for (int i = 0; i < 4; ++i) cnt[tid + i * 1024] = 0;
    #pragma unroll
    for (int i = 0; i < 16; ++i) H[tid + i * 1024] = 0;   // 16384 of 16400
    if (tid < NCH * (CC + 1) - 16 * 1024) H[16 * 1024 + tid] = 0;
    __syncthreads();

    // 2. combine 16 partial keys for channel c = tid -> winner -> LDS hist
    {
        u64 bestk = 0;
        const u64* pk = pkeys + (size_t)b * NCH * CC + tid;
        #pragma unroll
        for (int k = 0; k < NCH; ++k) {
            u64 key = pk[k * CC];
            bestk = (key > bestk) ? key : bestk;
        }
        int idx = 4095 - (int)(bestk & 0xFFFu);
        atomicAdd(&cnt[idx], 1);
    }
    __syncthreads();

    // 3. write counts (coalesced float4) + per-chunk hist (wave w <-> chunk w)
    {
        float4 cf;
        cf.x = (float)cnt[4 * tid + 0];
        cf.y = (float)cnt[4 * tid + 1];
        cf.z = (float)cnt[4 * tid + 2];
        cf.w = (float)cnt[4 * tid + 3];
        *(float4*)(counts + (size_t)b * NN + 4 * tid) = cf;

        int h0 = 0, h1 = 0;
        #pragma unroll
        for (int r = 0; r < 4; ++r) {
            int ci = cnt[wv * CHK + r * 64 + lane];
            u64 m0 = __ballot(ci == 0);
            u64 m1 = __ballot(ci == 1);
            if (lane == 0) { h0 += (int)__popcll(m0); h1 += (int)__popcll(m1); }
            if (ci > 1) atomicAdd(&H[wv * (CC + 1) + ci], 1);
        }
        if (lane == 0) {           // bins 0/1 never touched by the atomics
            H[wv * (CC + 1) + 0] = h0;
            H[wv * (CC + 1) + 1] = h1;
        }
    }
    __syncthreads();

    // 4. transform H[w][v] -> prefix over chunks (per value v=tid); row total
    //    g_v; entropy partial; wave-level shuffle scan + reduce (no barriers)
    int g_v, run1024 = 0;
    {
        int run = 0;
        #pragma unroll
        for (int w = 0; w < NCH; ++w) {
            int t = H[w * (CC + 1) + tid];
            H[w * (CC + 1) + tid] = run;     // prefix of chunks < w
            run += t;
        }
        g_v = run;
        if (tid == 0) {                      // value bin 1024 handled by thread 0
            int run2 = 0;
            #pragma unroll
            for (int w = 0; w < NCH; ++w) {
                int t = H[w * (CC + 1) + CC];
                H[w * (CC + 1) + CC] = run2;
                run2 += t;
            }
            run1024 = run2;
        }
    }
    const float S = 1024.0f + 4096.0f * 1e-6f;   // sum(counts)+N*eps exactly
    float e = 0.f;
    if (g_v) {
        float p = ((float)tid + 1e-6f) / S;
        e = (float)g_v * p * log2f(p);
    }
    if (tid == 0 && run1024) {
        float p = (1024.0f + 1e-6f) / S;
        e += (float)run1024 * p * log2f(p);
    }
    int incl = g_v;                              // wave inclusive scan
    #pragma unroll
    for (int d = 1; d < 64; d <<= 1) {
        int t = __shfl_up(incl, d, 64);
        if (lane >= d) incl += t;
    }
    float er = e;                                // wave entropy reduce
    #pragma unroll
    for (int d = 32; d > 0; d >>= 1)
        er += __shfl_down(er, d, 64);
    if (lane == 63) wsum[wv] = incl;
    if (lane == 0)  esum[wv] = er;
    __syncthreads();

    // 5. wave0: exclusive scan of 16 wave sums; wave1: entropy total -> ent[b]
    if (wv == 0) {
        int v = (lane < 16) ? wsum[lane] : 0;
        int inc2 = v;
        #pragma unroll
        for (int d = 1; d < 16; d <<= 1) {
            int t = __shfl_up(inc2, d, 64);
            if (lane >= d) inc2 += t;
        }
        if (lane < 16) wsum[lane] = inc2 - v;    // exclusive wave prefix
    } else if (wv == 1) {
        float v = (lane < 16) ? esum[lane] : 0.f;
        #pragma unroll
        for (int d = 8; d > 0; d >>= 1)
            v += __shfl_down(v, d, 64);
        if (lane == 0) ent[b] = -v / 12.0f;      // log2(4096) = 12
    }
    __syncthreads();

    // 6. exclusive value prefix -> LDS
    exvs[tid] = incl - g_v + wsum[wv];
    if (tid == 0) exvs[CC] = NN - run1024;
    __syncthreads();

    // 7. stable placement: wave w <-> chunk w; 4 batches of 64 points in index
    //    order. Rank among equals within batch via match-any ballot; rank
    //    across batches via per-(chunk,value) cursor in H (wave-private row).
    {
        const u64 ltmask = (1ull << lane) - 1ull;
        int* curw = &H[wv * (CC + 1)];
        float* orow = imp2 + (size_t)b * NN;
        for (int r = 0; r < 4; ++r) {
            const int n = wv * CHK + r * 64 + lane;
            const int ci = cnt[n];
            // match-any: eq = mask of lanes whose ci equals mine
            u64 eq = 0, todo = ~0ull;
            while (true) {                        // ~#distinct values iterations
                int src = (int)__builtin_ctzll(todo);
                int v0 = __shfl(ci, src, 64);
                u64 m = __ballot(ci == v0);
                if (ci == v0) eq = m;
                todo &= ~m;
                if (todo == 0ull) break;
            }
            int rank = (int)__popcll(eq & ltmask);
            int c0 = curw[ci];                    // broadcast-ish LDS read
            orow[c0 + exvs[ci] + rank] = (float)n;
            if ((eq >> lane) == 1ull)             // highest equal lane updates
                curw[ci] = c0 + (int)__popcll(eq);
        }
    }
}

extern "C" void kernel_launch(void* const* d_in, const int* in_sizes, int n_in,
                              void* d_out, int out_size, void* d_ws, size_t ws_size,
                              hipStream_t stream) {
    const float* x = (const float*)d_in[0];    // [32,3,4096]
    const float* W = (const float*)d_in[1];    // [1024,3]
    float* out    = (float*)d_out;
    float* out_x  = out;                        // 393216
    float* counts = out + (size_t)BB * 3 * NN;  // 131072
    float* imp2   = counts + (size_t)BB * NN;   // 131072
    float* ent    = imp2 + (size_t)BB * NN;     // 32

    u64* pkeys = (u64*)d_ws;                    // 32*16*1024 u64 = 4 MB

    k1_argmax_partial<<<BB * NCH, 512, 0, stream>>>(x, W, out_x, pkeys);
    k2_row_all<<<BB, 1024, 0, stream>>>(pkeys, counts, imp2, ent);
}